// Round 1
// baseline (141.114 us; speedup 1.0000x reference)
//
#include <hip/hip_runtime.h>

// CenterLoss: B=1024, C=100000, D=256.
// loss = (1/B) * sum_i clamp(||x_i - c_{labels[i]}||^2, 1e-12, 1e12) + (C-1)*1e-12
// The full BxC distmat in the reference is masked to one column per row, so
// only the label-gathered distances matter (+ the clamp-floor constant).

#define CL_B 1024
#define CL_C 100000
#define CL_D 256
#define CLAMP_MIN 1e-12f
#define CLAMP_MAX 1e12f

__global__ __launch_bounds__(256) void center_loss_kernel(
    const float* __restrict__ x,
    const int* __restrict__ labels,
    const float* __restrict__ centers,
    float* __restrict__ out) {
    // One 64-lane wave per row. 256 threads/block = 4 rows/block.
    const int tid  = blockIdx.x * blockDim.x + threadIdx.x;
    const int row  = tid >> 6;          // wave index = row
    const int lane = threadIdx.x & 63;  // lane within wave

    if (row >= CL_B) return;

    const int label = labels[row];

    // Each lane handles 4 contiguous floats: D = 256 = 64 lanes * 4.
    const float4 xv = *reinterpret_cast<const float4*>(
        x + (size_t)row * CL_D + (size_t)lane * 4);
    const float4 cv = *reinterpret_cast<const float4*>(
        centers + (size_t)label * CL_D + (size_t)lane * 4);

    const float d0 = xv.x - cv.x;
    const float d1 = xv.y - cv.y;
    const float d2 = xv.z - cv.z;
    const float d3 = xv.w - cv.w;
    float s = d0 * d0 + d1 * d1 + d2 * d2 + d3 * d3;

    // Wave-64 butterfly reduction.
    #pragma unroll
    for (int off = 32; off > 0; off >>= 1) {
        s += __shfl_down(s, off, 64);
    }

    if (lane == 0) {
        const float d = fminf(fmaxf(s, CLAMP_MIN), CLAMP_MAX);
        atomicAdd(out, d * (1.0f / (float)CL_B));
    }

    // One thread adds the clamp-floor constant from the (C-1) masked columns
    // per row: B*(C-1)*1e-12 / B = (C-1)*1e-12.
    if (tid == 0) {
        atomicAdd(out, (float)((double)(CL_C - 1) * 1e-12));
    }
}

extern "C" void kernel_launch(void* const* d_in, const int* in_sizes, int n_in,
                              void* d_out, int out_size, void* d_ws, size_t ws_size,
                              hipStream_t stream) {
    const float* x       = (const float*)d_in[0];
    const int*   labels  = (const int*)d_in[1];
    const float* centers = (const float*)d_in[2];
    float*       out     = (float*)d_out;

    // d_out is poisoned to 0xAA before every call; zero it first.
    hipMemsetAsync(out, 0, sizeof(float), stream);

    // 1024 rows, 1 wave/row, 4 waves/block -> 256 blocks.
    const int threads = 256;
    const int blocks  = CL_B / 4;
    center_loss_kernel<<<blocks, threads, 0, stream>>>(x, labels, centers, out);
}

// Round 5
// 130.928 us; speedup vs baseline: 1.0778x; 1.0778x over previous
//
#include <hip/hip_runtime.h>

// CenterLoss: B=1024, C=100000, D=256.
// loss = (1/B) * sum_i clamp(||x_i - c_{labels[i]}||^2, 1e-12, 1e12) + (C-1)*1e-12
// (the constant term is the clamp-floor contribution of the B*(C-1) masked
//  zeros in the reference's full distmat, divided by B).
//
// Two-stage reduction, no atomics, no memset node:
//   stage 1: 256 blocks x 256 threads; block b computes rows 4b..4b+3
//            (one 64-lane wave per row), block-reduces, writes partial[b].
//   stage 2: 1 block x 256 threads; reduces 256 partials, adds the constant,
//            stores the scalar output directly (overwrites poisoned d_out).

#define CL_B 1024
#define CL_C 100000
#define CL_D 256
#define CLAMP_MIN 1e-12f
#define CLAMP_MAX 1e12f

__global__ __launch_bounds__(256) void center_loss_stage1(
    const float* __restrict__ x,
    const int* __restrict__ labels,
    const float* __restrict__ centers,
    float* __restrict__ partials) {
    const int wave = threadIdx.x >> 6;               // 0..3
    const int lane = threadIdx.x & 63;
    const int row  = blockIdx.x * 4 + wave;          // 0..1023

    const int label = labels[row];

    // Each lane handles 4 contiguous floats: D = 256 = 64 lanes * 4.
    const float4 xv = *reinterpret_cast<const float4*>(
        x + (size_t)row * CL_D + (size_t)lane * 4);
    const float4 cv = *reinterpret_cast<const float4*>(
        centers + (size_t)label * CL_D + (size_t)lane * 4);

    const float d0 = xv.x - cv.x;
    const float d1 = xv.y - cv.y;
    const float d2 = xv.z - cv.z;
    const float d3 = xv.w - cv.w;
    float s = d0 * d0 + d1 * d1 + d2 * d2 + d3 * d3;

    // Wave-64 butterfly reduction -> full row distance in lane 0.
    #pragma unroll
    for (int off = 32; off > 0; off >>= 1) {
        s += __shfl_down(s, off, 64);
    }

    __shared__ float wsum[4];
    if (lane == 0) {
        // clamp is per-row (per distmat element) in the reference.
        wsum[wave] = fminf(fmaxf(s, CLAMP_MIN), CLAMP_MAX);
    }
    __syncthreads();

    if (threadIdx.x == 0) {
        partials[blockIdx.x] = wsum[0] + wsum[1] + wsum[2] + wsum[3];
    }
}

__global__ __launch_bounds__(256) void center_loss_stage2(
    const float* __restrict__ partials,
    float* __restrict__ out) {
    const int wave = threadIdx.x >> 6;
    const int lane = threadIdx.x & 63;

    float s = partials[threadIdx.x];   // 256 partials, one per thread

    #pragma unroll
    for (int off = 32; off > 0; off >>= 1) {
        s += __shfl_down(s, off, 64);
    }

    __shared__ float wsum[4];
    if (lane == 0) wsum[wave] = s;
    __syncthreads();

    if (threadIdx.x == 0) {
        const float total = wsum[0] + wsum[1] + wsum[2] + wsum[3];
        out[0] = total * (1.0f / (float)CL_B)
               + (float)((double)(CL_C - 1) * 1e-12);
    }
}

extern "C" void kernel_launch(void* const* d_in, const int* in_sizes, int n_in,
                              void* d_out, int out_size, void* d_ws, size_t ws_size,
                              hipStream_t stream) {
    const float* x       = (const float*)d_in[0];
    const int*   labels  = (const int*)d_in[1];
    const float* centers = (const float*)d_in[2];
    float*       out     = (float*)d_out;
    float*       partials = (float*)d_ws;   // 256 floats of scratch

    center_loss_stage1<<<CL_B / 4, 256, 0, stream>>>(x, labels, centers, partials);
    center_loss_stage2<<<1, 256, 0, stream>>>(partials, out);
}